// Round 9
// baseline (276.582 us; speedup 1.0000x reference)
//
#include <hip/hip_runtime.h>

#define SEQ  4096
#define DMODEL 1024
#define QTOT 16384           // B*S
#define QSCALE 0.18033688011112042f   // (1/sqrt(64)) * log2(e), folded into Q

typedef __bf16 bf16x8 __attribute__((ext_vector_type(8)));
typedef unsigned short u16x8 __attribute__((ext_vector_type(8)));
typedef float f32x4 __attribute__((ext_vector_type(4)));

// ---------- helpers ----------
static __device__ __forceinline__ unsigned short f2bfbits(float f) {
    unsigned int u = __builtin_bit_cast(unsigned int, f);
    unsigned int lsb = (u >> 16) & 1u;
    u += 0x7fffu + lsb;                      // round-to-nearest-even
    return (unsigned short)(u >> 16);
}

static __device__ __forceinline__ bf16x8 ld_frag(const unsigned short* p) {
    uint4 u = *reinterpret_cast<const uint4*>(p);
    return __builtin_bit_cast(bf16x8, u);
}

// ---------- kernel 1: weights -> bf16, pre-swizzled into MFMA B-fragment order ----------
__global__ void prep_weights(const float* __restrict__ Wq,
                             const float* __restrict__ Wk,
                             const float* __restrict__ Wv,
                             unsigned short* __restrict__ WtS) {
    int o = blockIdx.x * 256 + threadIdx.x;      // 192*1024 total
    int f = o >> 9, q = o & 511;
    int lane = q >> 3, j = q & 7;
    int kc = f / 12, nt = f - kc * 12;
    int n = nt * 16 + (lane & 15);
    int k = kc * 32 + (lane >> 4) * 8 + j;
    float v;
    if (n < 64)       v = Wq[k * 64 + n];
    else if (n < 128) v = Wk[k * 64 + (n - 64)];
    else              v = Wv[k * 64 + (n - 128)];
    WtS[o] = f2bfbits(v);
}

// ---------- kernel 2: QKV projection ----------
// grid 1024 x 512 thr; block = 16 tokens; wave (kq,nh) = k-quarter x n-half.
// V written in MFMA B-fragment order (VF) so attn's V loads are coalesced.
__global__ __launch_bounds__(512) void proj(
        const float* __restrict__ emb, const unsigned short* __restrict__ WtS,
        const float* __restrict__ bq, const float* __restrict__ bk,
        const float* __restrict__ bv,
        unsigned short* __restrict__ Qb, unsigned short* __restrict__ Kb,
        unsigned short* __restrict__ VF) {
    __shared__ __align__(16) float red[4][64 * 25];

    const int tid = threadIdx.x;
    const int w = tid >> 6, lane = tid & 63;
    const int c = lane & 15, qd = lane >> 4;
    const int kq = w >> 1, nh = w & 1;
    const int tb = blockIdx.x;

    const float* ap = emb + (size_t)(tb * 16 + c) * DMODEL + kq * 256 + qd * 8;
    const unsigned short* wp = WtS + (size_t)(kq * 8) * 6144 + (nh * 6) * 512 + lane * 8;

    f32x4 acc[6];
#pragma unroll
    for (int i = 0; i < 6; i++) acc[i] = (f32x4){0.f, 0.f, 0.f, 0.f};

    float4 e0a = *reinterpret_cast<const float4*>(ap);
    float4 e0b = *reinterpret_cast<const float4*>(ap + 4);
    float4 e1a = *reinterpret_cast<const float4*>(ap + 32);
    float4 e1b = *reinterpret_cast<const float4*>(ap + 36);
    bf16x8 wc[6], wn[6];
#pragma unroll
    for (int nt = 0; nt < 6; nt++) wc[nt] = ld_frag(wp + nt * 512);

#pragma unroll
    for (int s = 0; s < 8; s++) {
        if (s < 7) {
#pragma unroll
            for (int nt = 0; nt < 6; nt++)
                wn[nt] = ld_frag(wp + (s + 1) * 6144 + nt * 512);
        } else {
#pragma unroll
            for (int nt = 0; nt < 6; nt++) wn[nt] = wc[nt];
        }
        float4 e2a, e2b;
        if (s < 6) {
            e2a = *reinterpret_cast<const float4*>(ap + (s + 2) * 32);
            e2b = *reinterpret_cast<const float4*>(ap + (s + 2) * 32 + 4);
        } else { e2a = e1a; e2b = e1b; }

        u16x8 at;
        at[0] = f2bfbits(e0a.x); at[1] = f2bfbits(e0a.y);
        at[2] = f2bfbits(e0a.z); at[3] = f2bfbits(e0a.w);
        at[4] = f2bfbits(e0b.x); at[5] = f2bfbits(e0b.y);
        at[6] = f2bfbits(e0b.z); at[7] = f2bfbits(e0b.w);
        bf16x8 af = __builtin_bit_cast(bf16x8, at);

#pragma unroll
        for (int nt = 0; nt < 6; nt++)
            acc[nt] = __builtin_amdgcn_mfma_f32_16x16x32_bf16(af, wc[nt], acc[nt], 0, 0, 0);

        e0a = e1a; e0b = e1b; e1a = e2a; e1b = e2b;
#pragma unroll
        for (int nt = 0; nt < 6; nt++) wc[nt] = wn[nt];
    }

    // tree-merge the 4 k-partials within each n-half
    if (kq >= 2) {
        float* rp = &red[nh * 2 + (kq - 2)][lane * 25];
#pragma unroll
        for (int i = 0; i < 6; i++) *reinterpret_cast<f32x4*>(rp + i * 4) = acc[i];
    }
    __syncthreads();
    if (kq < 2) {
        float* rp = &red[nh * 2 + kq][lane * 25];
#pragma unroll
        for (int i = 0; i < 6; i++) acc[i] += *reinterpret_cast<const f32x4*>(rp + i * 4);
    }
    __syncthreads();
    if (kq == 1) {
        float* rp = &red[nh * 2][lane * 25];
#pragma unroll
        for (int i = 0; i < 6; i++) *reinterpret_cast<f32x4*>(rp + i * 4) = acc[i];
    }
    __syncthreads();
    if (kq == 0) {
        float* rp = &red[nh * 2][lane * 25];
#pragma unroll
        for (int i = 0; i < 6; i++) acc[i] += *reinterpret_cast<const f32x4*>(rp + i * 4);

#pragma unroll
        for (int nt = 0; nt < 6; nt++) {
            int n = nh * 96 + nt * 16 + c;
            float bias = (n < 64) ? bq[n] : (n < 128) ? bk[n - 64] : bv[n - 128];
            float fac = (n < 64) ? QSCALE : 1.0f;
#pragma unroll
            for (int r = 0; r < 4; r++) {
                int token = tb * 16 + qd * 4 + r;
                unsigned short bits = f2bfbits((acc[nt][r] + bias) * fac);
                if (n < 64)        Qb[(size_t)token * 64 + n] = bits;
                else if (n < 128)  Kb[(size_t)token * 64 + (n - 64)] = bits;
                else {
                    int bb = token >> 12, t = token & 4095, v = n - 128;
                    size_t off = ((size_t)(bb * 64 + (t >> 6)) * 4 + (v >> 4)) * 1024
                               + ((t >> 5) & 1) * 512
                               + (((t & 31) >> 3) * 16 + (v & 15)) * 8 + (t & 7);
                    VF[off] = bits;
                }
            }
        }
    }
}

// ---------- kernel 3: flash attention, 32-t steps, coalesced V-frags ----------
// 512 thr = 8 waves; block = 64 q x tlen t; wave slice tlen/8, steps of 32 t.
// P via per-wave LDS rows 64 x stride 40 (16B-aligned, 2-way banks = free).
template <int STEPS>
__global__ __launch_bounds__(512, 4) void attn(
        const unsigned short* __restrict__ Qb, const unsigned short* __restrict__ Kb,
        const unsigned short* __restrict__ VF,
        float* __restrict__ accP, float* __restrict__ lP,
        float* __restrict__ outDirect, int tlen) {
    __shared__ __align__(16) unsigned short Pl[8][64 * 40];  // 40960 B, aliased as reduce buf
    __shared__ float l_all[8][64];

    const int tid = threadIdx.x;
    const int w = tid >> 6, lane = tid & 63;
    const int c = lane & 15, qd = lane >> 4;
    const int g3 = blockIdx.x & 7;               // XCD pin
    const int b = g3 >> 1;
    int tsp, qblk;
    if (outDirect) { tsp = 0; qblk = ((blockIdx.x >> 3) << 1) | (g3 & 1); }
    else           { tsp = g3 & 1; qblk = blockIdx.x >> 3; }
    const int qbase = qblk * 64;
    const int tstart = tsp * tlen + w * (tlen >> 3);

    // Q A-fragments (shared by all 8 waves -> L1), pre-scaled by QSCALE
    bf16x8 aq0[4], aq1[4];
#pragma unroll
    for (int qs = 0; qs < 4; qs++) {
        const unsigned short* Qp = Qb + ((size_t)(b << 12) + qbase + qs * 16 + c) * 64 + qd * 8;
        aq0[qs] = ld_frag(Qp);
        aq1[qs] = ld_frag(Qp + 32);
    }

    f32x4 acc[16];
#pragma unroll
    for (int i = 0; i < 16; i++) acc[i] = (f32x4){0.f, 0.f, 0.f, 0.f};
    float lsum[4][4];
#pragma unroll
    for (int qs = 0; qs < 4; qs++)
#pragma unroll
        for (int r = 0; r < 4; r++) lsum[qs][r] = 0.f;

    unsigned short* myP = &Pl[w][0];

#pragma unroll 2
    for (int s = 0; s < STEPS; s++) {
        const int t0 = tstart + s * 32;

        // K B-frags (semi-coalesced) and V B-frags (fully coalesced) up top
        const unsigned short* Kt = Kb + ((size_t)(b << 12) + t0) * 64;
        bf16x8 bk0[2], bk1[2];
#pragma unroll
        for (int ts = 0; ts < 2; ts++) {
            bk0[ts] = ld_frag(Kt + (ts * 16 + c) * 64 + qd * 8);
            bk1[ts] = ld_frag(Kt + (ts * 16 + c) * 64 + 32 + qd * 8);
        }
        const unsigned short* Vt = VF + ((size_t)(b * 64 + (t0 >> 6)) * 4) * 1024
                                 + ((t0 >> 5) & 1) * 512 + lane * 8;
        bf16x8 bv[4];
#pragma unroll
        for (int nt = 0; nt < 4; nt++) bv[nt] = ld_frag(Vt + nt * 1024);

        // scores -> exp2 -> P (rows 64 x 32 cols, stride 40)
#pragma unroll
        for (int qs = 0; qs < 4; qs++) {
#pragma unroll
            for (int ts = 0; ts < 2; ts++) {
                f32x4 z = (f32x4){0.f, 0.f, 0.f, 0.f};
                z = __builtin_amdgcn_mfma_f32_16x16x32_bf16(aq0[qs], bk0[ts], z, 0, 0, 0);
                z = __builtin_amdgcn_mfma_f32_16x16x32_bf16(aq1[qs], bk1[ts], z, 0, 0, 0);
#pragma unroll
                for (int r = 0; r < 4; r++) {
                    float p = __builtin_amdgcn_exp2f(z[r]);
                    lsum[qs][r] += p;
                    myP[(qs * 16 + qd * 4 + r) * 40 + ts * 16 + c] = f2bfbits(p);
                }
            }
        }

        // PV: one K=32 MFMA per (qs,nt)
#pragma unroll
        for (int qs = 0; qs < 4; qs++) {
            bf16x8 ap = ld_frag(&myP[(qs * 16 + c) * 40 + qd * 8]);
#pragma unroll
            for (int nt = 0; nt < 4; nt++)
                acc[qs * 4 + nt] = __builtin_amdgcn_mfma_f32_16x16x32_bf16(
                    ap, bv[nt], acc[qs * 4 + nt], 0, 0, 0);
        }
    }

    // l reduction across the 16 column lanes
#pragma unroll
    for (int off = 1; off < 16; off <<= 1)
#pragma unroll
        for (int qs = 0; qs < 4; qs++)
#pragma unroll
            for (int r = 0; r < 4; r++) lsum[qs][r] += __shfl_xor(lsum[qs][r], off);
    if (c == 0) {
#pragma unroll
        for (int qs = 0; qs < 4; qs++)
#pragma unroll
            for (int r = 0; r < 4; r++)
                l_all[w][qs * 16 + qd * 4 + r] = lsum[qs][r];
    }

    // tree-reduce acc over 8 waves in TWO passes of 8 f32x4 (buffer aliases Pl)
    float* red = (float*)&Pl[0][0];              // 4 slots x 64 lanes x stride 34
#pragma unroll
    for (int p = 0; p < 2; p++) {
        f32x4* a = &acc[p * 8];
        __syncthreads();
        if (w >= 4) {
            float* rp = red + (w - 4) * 2176 + lane * 34;
#pragma unroll
            for (int i = 0; i < 8; i++) *reinterpret_cast<f32x4*>(rp + i * 4) = a[i];
        }
        __syncthreads();
        if (w < 4) {
            float* rp = red + w * 2176 + lane * 34;
#pragma unroll
            for (int i = 0; i < 8; i++) a[i] += *reinterpret_cast<const f32x4*>(rp + i * 4);
        }
        __syncthreads();
        if (w == 2 || w == 3) {
            float* rp = red + (w - 2) * 2176 + lane * 34;
#pragma unroll
            for (int i = 0; i < 8; i++) *reinterpret_cast<f32x4*>(rp + i * 4) = a[i];
        }
        __syncthreads();
        if (w < 2) {
            float* rp = red + w * 2176 + lane * 34;
#pragma unroll
            for (int i = 0; i < 8; i++) a[i] += *reinterpret_cast<const f32x4*>(rp + i * 4);
        }
        __syncthreads();
        if (w == 1) {
            float* rp = red + lane * 34;
#pragma unroll
            for (int i = 0; i < 8; i++) *reinterpret_cast<f32x4*>(rp + i * 4) = a[i];
        }
        __syncthreads();
        if (w == 0) {
            float* rp = red + lane * 34;
#pragma unroll
            for (int i = 0; i < 8; i++) a[i] += *reinterpret_cast<const f32x4*>(rp + i * 4);
        }
    }

    if (w == 0) {
#pragma unroll
        for (int qs = 0; qs < 4; qs++)
#pragma unroll
            for (int r = 0; r < 4; r++) {
                int q = qs * 16 + qd * 4 + r;
                float l = 0.f;
#pragma unroll
                for (int ww = 0; ww < 8; ww++) l += l_all[ww][q];
                size_t brow = (size_t)(b << 12) + qbase + q;
                if (outDirect) {
                    float inv = 1.0f / l;
#pragma unroll
                    for (int nt = 0; nt < 4; nt++)
                        outDirect[brow * 64 + nt * 16 + c] = acc[qs * 4 + nt][r] * inv;
                } else {
#pragma unroll
                    for (int nt = 0; nt < 4; nt++)
                        accP[((size_t)tsp * QTOT + brow) * 64 + nt * 16 + c] = acc[qs * 4 + nt][r];
                    if (c == 0) lP[(size_t)tsp * QTOT + brow] = l;
                }
            }
    }
}

// ---------- kernel 4: merge the 2 t-split partials ----------
__global__ __launch_bounds__(256) void merge_attn(
        const float* __restrict__ accP, const float* __restrict__ lP,
        float* __restrict__ out) {
    int idx4 = (blockIdx.x * 256 + threadIdx.x) * 4;   // over QTOT*64
    int q = idx4 >> 6;
    float4 a0 = *reinterpret_cast<const float4*>(accP + idx4);
    float4 a1 = *reinterpret_cast<const float4*>(accP + (size_t)QTOT * 64 + idx4);
    float inv = 1.0f / (lP[q] + lP[QTOT + q]);
    float4 o = {(a0.x + a1.x) * inv, (a0.y + a1.y) * inv,
                (a0.z + a1.z) * inv, (a0.w + a1.w) * inv};
    *reinterpret_cast<float4*>(out + idx4) = o;
}

// ---------- launch ----------
extern "C" void kernel_launch(void* const* d_in, const int* in_sizes, int n_in,
                              void* d_out, int out_size, void* d_ws, size_t ws_size,
                              hipStream_t stream) {
    const float* emb = (const float*)d_in[0];
    const float* Wq  = (const float*)d_in[1];
    const float* bq  = (const float*)d_in[2];
    const float* Wk  = (const float*)d_in[3];
    const float* bk  = (const float*)d_in[4];
    const float* Wv  = (const float*)d_in[5];
    const float* bv  = (const float*)d_in[6];
    float* out = (float*)d_out;

    unsigned short* ws = (unsigned short*)d_ws;
    unsigned short* WtS = ws;                      // 192*1024 ushort
    unsigned short* Qb = ws + 192 * 1024;          // QTOT*64 bf16
    unsigned short* Kb = Qb + QTOT * 64;           // QTOT*64 bf16
    unsigned short* VF = Kb + QTOT * 64;           // V in B-fragment order
    char* region = (char*)(VF + QTOT * 64);        // byte offset 6,684,672
    size_t avail = (ws_size > 6684672) ? ws_size - 6684672 : 0;
    size_t need = (size_t)2 * QTOT * 64 * 4 + (size_t)2 * QTOT * 4;  // 8.5 MB

    prep_weights<<<768, 256, 0, stream>>>(Wq, Wk, Wv, WtS);
    proj<<<1024, 512, 0, stream>>>(emb, WtS, bq, bk, bv, Qb, Kb, VF);

    if (avail >= need) {
        float* accP = (float*)region;
        float* lP   = accP + (size_t)2 * QTOT * 64;
        attn<8><<<512, 512, 0, stream>>>(Qb, Kb, VF, accP, lP, nullptr, 2048);
        merge_attn<<<(QTOT * 64) / 1024, 256, 0, stream>>>(accP, lP, out);
    } else {
        attn<16><<<256, 512, 0, stream>>>(Qb, Kb, VF, nullptr, nullptr, out, 4096);
    }
}